// Round 1
// baseline (233.114 us; speedup 1.0000x reference)
//
#include <hip/hip_runtime.h>
#include <hip/hip_bf16.h>

typedef __attribute__((ext_vector_type(8))) short short8;
typedef __attribute__((ext_vector_type(4))) float f32x4;
typedef unsigned short u16;
typedef unsigned int   u32;
typedef unsigned long long u64;
typedef unsigned char  u8;

#define NN 8192
#define THRESH 0.1f

__device__ __forceinline__ u16 f2bf(float f){
  __hip_bfloat16 h = __float2bfloat16(f);
  u16 u; __builtin_memcpy(&u, &h, 2); return u;
}

// ---- K1: normalize state rows: sn[i] = s[i]/(||s[i]||+1e-12) ----
__global__ __launch_bounds__(256) void k_norm(const float* __restrict__ st, float* __restrict__ sn){
  int i = blockIdx.x*256 + threadIdx.x;          // grid exactly covers 8192
  const float4* s4 = reinterpret_cast<const float4*>(st + i*16);
  float4 v[4]; float ss = 0.f;
  #pragma unroll
  for (int q=0;q<4;q++){ v[q]=s4[q]; ss += v[q].x*v[q].x+v[q].y*v[q].y+v[q].z*v[q].z+v[q].w*v[q].w; }
  float inv = 1.0f/(sqrtf(ss) + 1e-12f);
  float4* d4 = reinterpret_cast<float4*>(sn + i*16);
  #pragma unroll
  for (int q=0;q<4;q++){ float4 o; o.x=v[q].x*inv; o.y=v[q].y*inv; o.z=v[q].z*inv; o.w=v[q].w*inv; d4[q]=o; }
}

// ---- K2: adjacency bitmask (self-bit cleared) + deg_inv ----
// block: 32 rows x all j. LDS-staged s_j tiles; lane-broadcast reads.
__global__ __launch_bounds__(256) void k_mask(const float* __restrict__ sn, u32* __restrict__ mask,
                                              float* __restrict__ dinvF){
  __shared__ float sj[512*16];
  __shared__ u32 dcount[32];
  int tid = threadIdx.x;
  int i_loc = tid & 31, w2 = tid >> 5;
  int i_g = blockIdx.x*32 + i_loc;
  if (tid < 32) dcount[tid] = 0u;
  float si[16];
  #pragma unroll
  for (int q=0;q<4;q++){
    float4 v = reinterpret_cast<const float4*>(sn + i_g*16)[q];
    si[4*q]=v.x; si[4*q+1]=v.y; si[4*q+2]=v.z; si[4*q+3]=v.w;
  }
  u32 pc = 0;
  for (int jt = 0; jt < NN; jt += 512){
    __syncthreads();
    #pragma unroll
    for (int s=0;s<8;s++){                       // 2048 16B-chunks, swizzled write
      int c = tid + 256*s;
      int row = c >> 2, q = c & 3;
      float4 v = *reinterpret_cast<const float4*>(sn + (jt+row)*16 + q*4);
      *reinterpret_cast<float4*>(sj + row*16 + ((q ^ (row&3))<<2)) = v;
    }
    __syncthreads();
    #pragma unroll
    for (int wi=0; wi<2; wi++){
      int ww = w2 + wi*8;
      u32 word = 0u;
      #pragma unroll 8
      for (int b=0;b<32;b++){
        int jj = ww*32 + b;
        const float* rowp = sj + jj*16;
        float d = 0.f;
        #pragma unroll
        for (int q=0;q<4;q++){
          float4 v = *reinterpret_cast<const float4*>(rowp + ((q ^ (jj&3))<<2));
          d += si[4*q]*v.x + si[4*q+1]*v.y + si[4*q+2]*v.z + si[4*q+3]*v.w;
        }
        if (d*d >= THRESH) word |= (1u<<b);
      }
      int jg0 = jt + ww*32;
      u32 rel = (u32)(i_g - jg0);
      if (rel < 32u) word &= ~(1u<<rel);         // no self-loop
      pc += __popc(word);
      mask[i_g*256 + (jg0>>5)] = word;
    }
  }
  atomicAdd(&dcount[i_loc], pc);
  __syncthreads();
  if (tid < 32) dinvF[blockIdx.x*32 + tid] = 1.0f/((float)dcount[tid] + 1e-6f);
}

// ---- K3: Yt[f][j] = dinv[j] * sum_k X[j,k]*W[f,k]   (bf16, j-contiguous) ----
__global__ __launch_bounds__(128) void k_ygemm(const float* __restrict__ X, const float* __restrict__ W,
                                               const float* __restrict__ dinvF, u16* __restrict__ Yt){
  int tid = threadIdx.x;
  int lane = tid & 63;
  int r = lane & 15, g = lane >> 4;
  int wj = tid >> 6;
  int f0 = blockIdx.x * 32;
  int j0 = blockIdx.y * 128 + wj * 64;
  f32x4 acc[2][4] = {};
  #pragma unroll
  for (int k0 = 0; k0 < 256; k0 += 32){
    short8 a[2], b[4];
    #pragma unroll
    for (int af=0; af<2; af++){
      const float* p = W + (f0 + af*16 + r)*256 + k0 + g*8;
      float4 u = reinterpret_cast<const float4*>(p)[0];
      float4 v = reinterpret_cast<const float4*>(p)[1];
      short8 t;
      t[0]=(short)f2bf(u.x); t[1]=(short)f2bf(u.y); t[2]=(short)f2bf(u.z); t[3]=(short)f2bf(u.w);
      t[4]=(short)f2bf(v.x); t[5]=(short)f2bf(v.y); t[6]=(short)f2bf(v.z); t[7]=(short)f2bf(v.w);
      a[af] = t;
    }
    #pragma unroll
    for (int bf=0; bf<4; bf++){
      const float* p = X + (j0 + bf*16 + r)*256 + k0 + g*8;
      float4 u = reinterpret_cast<const float4*>(p)[0];
      float4 v = reinterpret_cast<const float4*>(p)[1];
      short8 t;
      t[0]=(short)f2bf(u.x); t[1]=(short)f2bf(u.y); t[2]=(short)f2bf(u.z); t[3]=(short)f2bf(u.w);
      t[4]=(short)f2bf(v.x); t[5]=(short)f2bf(v.y); t[6]=(short)f2bf(v.z); t[7]=(short)f2bf(v.w);
      b[bf] = t;
    }
    #pragma unroll
    for (int af=0; af<2; af++)
      #pragma unroll
      for (int bf=0; bf<4; bf++)
        acc[af][bf] = __builtin_amdgcn_mfma_f32_16x16x32_bf16(a[af], b[bf], acc[af][bf], 0, 0, 0);
  }
  float ds[4];
  #pragma unroll
  for (int bf=0;bf<4;bf++) ds[bf] = dinvF[j0 + bf*16 + r];
  #pragma unroll
  for (int af=0; af<2; af++)
    #pragma unroll
    for (int bf=0; bf<4; bf++)
      #pragma unroll
      for (int q=0;q<4;q++)
        Yt[(f0 + af*16 + g*4 + q)*NN + j0 + bf*16 + r] = f2bf(acc[af][bf][q] * ds[bf]);
}

// ---- K4: partial[z] = M[m-tile, k-slice] @ Yt^T  (mask bits -> bf16 A in regs) ----
__global__ __launch_bounds__(256) void k_agg(const u16* __restrict__ Yt, const u8* __restrict__ maskB,
                                             float* __restrict__ part){
  __shared__ u8  ldsB[128*128];   // B tile [n-local 128][k 64] bf16, chunk-XOR swizzled
  __shared__ u64 ldsM[128];       // mask bytes for 128 m-rows x 64 k-bits
  int tid = threadIdx.x;
  int lane = tid & 63, wid = tid >> 6;
  int r = lane & 15, g = lane >> 4;
  int wm = wid >> 1, wn = wid & 1;
  int m0 = blockIdx.x*128, n0 = blockIdx.y*128;
  int kbase = blockIdx.z*2048;
  f32x4 acc[4][4] = {};
  int srow = tid >> 1, shalf = tid & 1;
  for (int ks = 0; ks < 2048; ks += 64){
    int k0 = kbase + ks;
    #pragma unroll
    for (int cc=0; cc<4; cc++){
      int chunk = shalf*4 + cc;
      short8 v = *reinterpret_cast<const short8*>(Yt + (n0+srow)*NN + k0 + chunk*8);
      *reinterpret_cast<short8*>(ldsB + srow*128 + ((chunk ^ (srow&7))<<4)) = v;
    }
    if (tid < 128)
      ldsM[tid] = *reinterpret_cast<const u64*>(maskB + (size_t)(m0+tid)*1024 + (k0>>3));
    __syncthreads();
    #pragma unroll
    for (int kk=0; kk<2; kk++){
      short8 bfrag[4];
      #pragma unroll
      for (int nf=0; nf<4; nf++){
        int row = wn*64 + nf*16 + r;
        int chunk = kk*4 + g;
        bfrag[nf] = *reinterpret_cast<const short8*>(ldsB + row*128 + ((chunk ^ (row&7))<<4));
      }
      #pragma unroll
      for (int mf=0; mf<4; mf++){
        u32 mb = reinterpret_cast<const u8*>(ldsM)[(wm*64 + mf*16 + r)*8 + kk*4 + g];
        short8 a;
        #pragma unroll
        for (int e=0;e<8;e++) a[e] = (short)(((mb >> e) & 1u) ? 0x3F80 : 0);  // bf16 1.0 / 0
        #pragma unroll
        for (int nf=0; nf<4; nf++)
          acc[mf][nf] = __builtin_amdgcn_mfma_f32_16x16x32_bf16(a, bfrag[nf], acc[mf][nf], 0, 0, 0);
      }
    }
    __syncthreads();
  }
  float* dst = part + (size_t)blockIdx.z * (NN*256);
  #pragma unroll
  for (int mf=0; mf<4; mf++)
    #pragma unroll
    for (int nf=0; nf<4; nf++)
      #pragma unroll
      for (int q=0;q<4;q++){
        int row = m0 + wm*64 + mf*16 + g*4 + q;
        int col = n0 + wn*64 + nf*16 + r;
        dst[row*256 + col] = acc[mf][nf][q];
      }
}

// ---- K5: out = bias + sum_z partial[z] ----
__global__ __launch_bounds__(256) void k_reduce(const float* __restrict__ part, const float* __restrict__ bias,
                                                float* __restrict__ out){
  int i = blockIdx.x*256 + threadIdx.x;          // float4 index; grid exactly covers 524288
  float4 s0 = reinterpret_cast<const float4*>(part          )[i];
  float4 s1 = reinterpret_cast<const float4*>(part + 2097152)[i];
  float4 s2 = reinterpret_cast<const float4*>(part + 4194304)[i];
  float4 s3 = reinterpret_cast<const float4*>(part + 6291456)[i];
  float4 bb = reinterpret_cast<const float4*>(bias)[i & 63];
  float4 o;
  o.x = s0.x+s1.x+s2.x+s3.x+bb.x;
  o.y = s0.y+s1.y+s2.y+s3.y+bb.y;
  o.z = s0.z+s1.z+s2.z+s3.z+bb.z;
  o.w = s0.w+s1.w+s2.w+s3.w+bb.w;
  reinterpret_cast<float4*>(out)[i] = o;
}

extern "C" void kernel_launch(void* const* d_in, const int* in_sizes, int n_in,
                              void* d_out, int out_size, void* d_ws, size_t ws_size,
                              hipStream_t stream) {
  const float* X    = (const float*)d_in[0];   // node_features [8192,256]
  const float* S    = (const float*)d_in[1];   // states        [8192,16]
  const float* W    = (const float*)d_in[2];   // W             [256,256]
  const float* bias = (const float*)d_in[3];   // b             [256]
  float* out = (float*)d_out;
  char* ws = (char*)d_ws;
  // workspace layout (bytes)
  u32*   mask  = (u32*)  (ws + 0);         //  8 MiB  bitmask [8192][256 words]
  u16*   Yt    = (u16*)  (ws + 8388608);   //  4 MiB  bf16 [256][8192] = (deg_inv*X@W^T)^T
  float* snorm = (float*)(ws + 12582912);  // 512 KiB normalized states
  float* dinvF = (float*)(ws + 13107200);  //  32 KiB
  float* part  = (float*)(ws + 13139968);  //  32 MiB fp32 partials [4][8192][256]

  k_norm  <<<dim3(32),        dim3(256), 0, stream>>>(S, snorm);
  k_mask  <<<dim3(256),       dim3(256), 0, stream>>>(snorm, mask, dinvF);
  k_ygemm <<<dim3(8,64),      dim3(128), 0, stream>>>(X, W, dinvF, Yt);
  k_agg   <<<dim3(64,2,4),    dim3(256), 0, stream>>>(Yt, (const u8*)mask, part);
  k_reduce<<<dim3(2048),      dim3(256), 0, stream>>>(part, bias, out);
}

// Round 2
// 151.465 us; speedup vs baseline: 1.5391x; 1.5391x over previous
//
#include <hip/hip_runtime.h>
#include <hip/hip_bf16.h>

typedef __attribute__((ext_vector_type(8))) short short8;
typedef __attribute__((ext_vector_type(4))) float f32x4;
typedef unsigned short u16;
typedef unsigned int   u32;
typedef unsigned long long u64;
typedef unsigned char  u8;

#define NN 8192
#define THRESH 0.1f

__device__ __forceinline__ u16 f2bf(float f){
  __hip_bfloat16 h = __float2bfloat16(f);
  u16 u; __builtin_memcpy(&u, &h, 2); return u;
}

// ---- K1: normalize state rows: sn[i] = s[i]/(||s[i]||+1e-12) ----
__global__ __launch_bounds__(256) void k_norm(const float* __restrict__ st, float* __restrict__ sn){
  int i = blockIdx.x*256 + threadIdx.x;          // grid exactly covers 8192
  const float4* s4 = reinterpret_cast<const float4*>(st + i*16);
  float4 v[4]; float ss = 0.f;
  #pragma unroll
  for (int q=0;q<4;q++){ v[q]=s4[q]; ss += v[q].x*v[q].x+v[q].y*v[q].y+v[q].z*v[q].z+v[q].w*v[q].w; }
  float inv = 1.0f/(sqrtf(ss) + 1e-12f);
  float4* d4 = reinterpret_cast<float4*>(sn + i*16);
  #pragma unroll
  for (int q=0;q<4;q++){ float4 o; o.x=v[q].x*inv; o.y=v[q].y*inv; o.z=v[q].z*inv; o.w=v[q].w*inv; d4[q]=o; }
}

// ---- K2: adjacency bitmask, TRANSPOSED layout maskT[jword][i]; deg via int atomics ----
// wave = 64 consecutive i-rows (lane-owned si in VGPRs); j-chunk wave-uniform -> s_j in SGPRs.
__global__ __launch_bounds__(256) void k_maskT(const float* __restrict__ sn, u32* __restrict__ maskT,
                                               u32* __restrict__ degcnt){
  int tid  = threadIdx.x;
  int lane = tid & 63;
  int i_g  = blockIdx.x*64 + lane;               // this lane's row (same rows for all 4 waves)
  int jc   = __builtin_amdgcn_readfirstlane(blockIdx.y*4 + (tid >> 6)); // j-chunk 0..31
  float si[16];
  #pragma unroll
  for (int q=0;q<4;q++){
    float4 v = reinterpret_cast<const float4*>(sn + i_g*16)[q];
    si[4*q]=v.x; si[4*q+1]=v.y; si[4*q+2]=v.z; si[4*q+3]=v.w;
  }
  u32 pc = 0;
  #pragma unroll
  for (int w = 0; w < 8; ++w){
    int j0 = jc*256 + w*32;
    u32 word = 0u;
    #pragma unroll 4
    for (int b = 0; b < 32; ++b){
      const float* sp = sn + (j0 + b)*16;        // wave-uniform address -> s_load
      float d0 = sp[0] *si[0]  + sp[1] *si[1]  + sp[2] *si[2]  + sp[3] *si[3];
      float d1 = sp[4] *si[4]  + sp[5] *si[5]  + sp[6] *si[6]  + sp[7] *si[7];
      float d2 = sp[8] *si[8]  + sp[9] *si[9]  + sp[10]*si[10] + sp[11]*si[11];
      float d3 = sp[12]*si[12] + sp[13]*si[13] + sp[14]*si[14] + sp[15]*si[15];
      float d  = (d0+d1)+(d2+d3);
      word |= (d*d >= THRESH) ? (1u << b) : 0u;
    }
    u32 rel = (u32)(i_g - j0);
    if (rel < 32u) word &= ~(1u << rel);         // no self-loop
    pc += __popc(word);
    maskT[(size_t)(jc*8 + w)*NN + i_g] = word;   // coalesced: lanes contiguous in i
  }
  atomicAdd(&degcnt[i_g], pc);
}

// ---- K2b: dinv[i] = 1/(deg+eps) ----
__global__ __launch_bounds__(256) void k_dinv(const u32* __restrict__ degcnt, float* __restrict__ dinvF){
  int i = blockIdx.x*256 + threadIdx.x;
  dinvF[i] = 1.0f/((float)degcnt[i] + 1e-6f);
}

// ---- K3: Yt[f][j] = dinv[j] * sum_k X[j,k]*W[f,k]   (bf16, j-contiguous) ----
__global__ __launch_bounds__(128) void k_ygemm(const float* __restrict__ X, const float* __restrict__ W,
                                               const float* __restrict__ dinvF, u16* __restrict__ Yt){
  int tid = threadIdx.x;
  int lane = tid & 63;
  int r = lane & 15, g = lane >> 4;
  int wj = tid >> 6;
  int f0 = blockIdx.x * 32;
  int j0 = blockIdx.y * 128 + wj * 64;
  f32x4 acc[2][4] = {};
  #pragma unroll
  for (int k0 = 0; k0 < 256; k0 += 32){
    short8 a[2], b[4];
    #pragma unroll
    for (int af=0; af<2; af++){
      const float* p = W + (f0 + af*16 + r)*256 + k0 + g*8;
      float4 u = reinterpret_cast<const float4*>(p)[0];
      float4 v = reinterpret_cast<const float4*>(p)[1];
      short8 t;
      t[0]=(short)f2bf(u.x); t[1]=(short)f2bf(u.y); t[2]=(short)f2bf(u.z); t[3]=(short)f2bf(u.w);
      t[4]=(short)f2bf(v.x); t[5]=(short)f2bf(v.y); t[6]=(short)f2bf(v.z); t[7]=(short)f2bf(v.w);
      a[af] = t;
    }
    #pragma unroll
    for (int bf=0; bf<4; bf++){
      const float* p = X + (j0 + bf*16 + r)*256 + k0 + g*8;
      float4 u = reinterpret_cast<const float4*>(p)[0];
      float4 v = reinterpret_cast<const float4*>(p)[1];
      short8 t;
      t[0]=(short)f2bf(u.x); t[1]=(short)f2bf(u.y); t[2]=(short)f2bf(u.z); t[3]=(short)f2bf(u.w);
      t[4]=(short)f2bf(v.x); t[5]=(short)f2bf(v.y); t[6]=(short)f2bf(v.z); t[7]=(short)f2bf(v.w);
      b[bf] = t;
    }
    #pragma unroll
    for (int af=0; af<2; af++)
      #pragma unroll
      for (int bf=0; bf<4; bf++)
        acc[af][bf] = __builtin_amdgcn_mfma_f32_16x16x32_bf16(a[af], b[bf], acc[af][bf], 0, 0, 0);
  }
  float ds[4];
  #pragma unroll
  for (int bf=0;bf<4;bf++) ds[bf] = dinvF[j0 + bf*16 + r];
  #pragma unroll
  for (int af=0; af<2; af++)
    #pragma unroll
    for (int bf=0; bf<4; bf++)
      #pragma unroll
      for (int q=0;q<4;q++)
        Yt[(f0 + af*16 + g*4 + q)*NN + j0 + bf*16 + r] = f2bf(acc[af][bf][q] * ds[bf]);
}

// ---- K4: partial[z] = M[m-tile, k-slice] @ Yt^T  (mask bits -> bf16 A in regs) ----
__global__ __launch_bounds__(256) void k_agg(const u16* __restrict__ Yt, const u32* __restrict__ maskT,
                                             float* __restrict__ part){
  __shared__ u8  ldsB[128*128];   // B tile [n-local 128][k 64] bf16, chunk-XOR swizzled
  __shared__ u32 ldsM[2][128];    // mask words (k0..k0+63) for 128 m-rows
  int tid = threadIdx.x;
  int lane = tid & 63, wid = tid >> 6;
  int r = lane & 15, g = lane >> 4;
  int wm = wid >> 1, wn = wid & 1;
  int m0 = blockIdx.x*128, n0 = blockIdx.y*128;
  int kbase = blockIdx.z*2048;
  f32x4 acc[4][4] = {};
  int srow = tid >> 1, shalf = tid & 1;
  for (int ks = 0; ks < 2048; ks += 64){
    int k0 = kbase + ks;
    #pragma unroll
    for (int cc=0; cc<4; cc++){
      int chunk = shalf*4 + cc;
      short8 v = *reinterpret_cast<const short8*>(Yt + (n0+srow)*NN + k0 + chunk*8);
      *reinterpret_cast<short8*>(ldsB + srow*128 + ((chunk ^ (srow&7))<<4)) = v;
    }
    ldsM[tid>>7][tid&127] = maskT[(size_t)((k0>>5) + (tid>>7))*NN + m0 + (tid&127)];
    __syncthreads();
    #pragma unroll
    for (int kk=0; kk<2; kk++){
      short8 bfrag[4];
      #pragma unroll
      for (int nf=0; nf<4; nf++){
        int row = wn*64 + nf*16 + r;
        int chunk = kk*4 + g;
        bfrag[nf] = *reinterpret_cast<const short8*>(ldsB + row*128 + ((chunk ^ (row&7))<<4));
      }
      #pragma unroll
      for (int mf=0; mf<4; mf++){
        u32 mb = (ldsM[kk][wm*64 + mf*16 + r] >> (g*8)) & 0xffu;
        short8 a;
        #pragma unroll
        for (int e=0;e<8;e++) a[e] = (short)(((mb >> e) & 1u) ? 0x3F80 : 0);  // bf16 1.0 / 0
        #pragma unroll
        for (int nf=0; nf<4; nf++)
          acc[mf][nf] = __builtin_amdgcn_mfma_f32_16x16x32_bf16(a, bfrag[nf], acc[mf][nf], 0, 0, 0);
      }
    }
    __syncthreads();
  }
  float* dst = part + (size_t)blockIdx.z * (NN*256);
  #pragma unroll
  for (int mf=0; mf<4; mf++)
    #pragma unroll
    for (int nf=0; nf<4; nf++)
      #pragma unroll
      for (int q=0;q<4;q++){
        int row = m0 + wm*64 + mf*16 + g*4 + q;
        int col = n0 + wn*64 + nf*16 + r;
        dst[row*256 + col] = acc[mf][nf][q];
      }
}

// ---- K5: out = bias + sum_z partial[z] ----
__global__ __launch_bounds__(256) void k_reduce(const float* __restrict__ part, const float* __restrict__ bias,
                                                float* __restrict__ out){
  int i = blockIdx.x*256 + threadIdx.x;          // float4 index; grid exactly covers 524288
  float4 s0 = reinterpret_cast<const float4*>(part          )[i];
  float4 s1 = reinterpret_cast<const float4*>(part + 2097152)[i];
  float4 s2 = reinterpret_cast<const float4*>(part + 4194304)[i];
  float4 s3 = reinterpret_cast<const float4*>(part + 6291456)[i];
  float4 bb = reinterpret_cast<const float4*>(bias)[i & 63];
  float4 o;
  o.x = s0.x+s1.x+s2.x+s3.x+bb.x;
  o.y = s0.y+s1.y+s2.y+s3.y+bb.y;
  o.z = s0.z+s1.z+s2.z+s3.z+bb.z;
  o.w = s0.w+s1.w+s2.w+s3.w+bb.w;
  reinterpret_cast<float4*>(out)[i] = o;
}

extern "C" void kernel_launch(void* const* d_in, const int* in_sizes, int n_in,
                              void* d_out, int out_size, void* d_ws, size_t ws_size,
                              hipStream_t stream) {
  const float* X    = (const float*)d_in[0];   // node_features [8192,256]
  const float* S    = (const float*)d_in[1];   // states        [8192,16]
  const float* W    = (const float*)d_in[2];   // W             [256,256]
  const float* bias = (const float*)d_in[3];   // b             [256]
  float* out = (float*)d_out;
  char* ws = (char*)d_ws;
  // workspace layout (bytes)
  u32*   maskT = (u32*)  (ws + 0);         //  8 MiB  bitmask transposed [256 words][8192 i]
  u16*   Yt    = (u16*)  (ws + 8388608);   //  4 MiB  bf16 [256][8192] = (deg_inv*X@W^T)^T
  float* snorm = (float*)(ws + 12582912);  // 512 KiB normalized states
  float* dinvF = (float*)(ws + 13107200);  //  32 KiB
  u32*   degcnt= (u32*)  (ws + 13139968);  //  32 KiB
  float* part  = (float*)(ws + 13172736);  //  32 MiB fp32 partials [4][8192][256]

  hipMemsetAsync(degcnt, 0, 8192*sizeof(u32), stream);
  k_norm  <<<dim3(32),        dim3(256), 0, stream>>>(S, snorm);
  k_maskT <<<dim3(128,8),     dim3(256), 0, stream>>>(snorm, maskT, degcnt);
  k_dinv  <<<dim3(32),        dim3(256), 0, stream>>>(degcnt, dinvF);
  k_ygemm <<<dim3(8,64),      dim3(128), 0, stream>>>(X, W, dinvF, Yt);
  k_agg   <<<dim3(64,2,4),    dim3(256), 0, stream>>>(Yt, maskT, part);
  k_reduce<<<dim3(2048),      dim3(256), 0, stream>>>(part, bias, out);
}

// Round 3
// 118.182 us; speedup vs baseline: 1.9725x; 1.2816x over previous
//
#include <hip/hip_runtime.h>
#include <hip/hip_bf16.h>

typedef __attribute__((ext_vector_type(8))) short short8;
typedef __attribute__((ext_vector_type(4))) float f32x4;
typedef unsigned short u16;
typedef unsigned int   u32;
typedef unsigned long long u64;
typedef unsigned char  u8;

#define NN 8192
#define THRESH 0.1f

__device__ __forceinline__ u16 f2bf(float f){
  __hip_bfloat16 h = __float2bfloat16(f);
  u16 u; __builtin_memcpy(&u, &h, 2); return u;
}

// ---- K1: normalize state rows: sn[i] = s[i]/(||s[i]||+1e-12) ----
__global__ __launch_bounds__(256) void k_norm(const float* __restrict__ st, float* __restrict__ sn){
  int i = blockIdx.x*256 + threadIdx.x;          // grid exactly covers 8192
  const float4* s4 = reinterpret_cast<const float4*>(st + i*16);
  float4 v[4]; float ss = 0.f;
  #pragma unroll
  for (int q=0;q<4;q++){ v[q]=s4[q]; ss += v[q].x*v[q].x+v[q].y*v[q].y+v[q].z*v[q].z+v[q].w*v[q].w; }
  float inv = 1.0f/(sqrtf(ss) + 1e-12f);
  float4* d4 = reinterpret_cast<float4*>(sn + i*16);
  #pragma unroll
  for (int q=0;q<4;q++){ float4 o; o.x=v[q].x*inv; o.y=v[q].y*inv; o.z=v[q].z*inv; o.w=v[q].w*inv; d4[q]=o; }
}

// ---- K2: symmetric tile mask. Wave = 1 tile of 128 i (2 rows/lane) x 64 j.
// Upper-triangle tiles only (J0 >= I0); per-lane words give mask[i][j-bits],
// __ballot gives transposed mask[j][i-bits] for free.
__global__ __launch_bounds__(256) void k_maskT2(const float* __restrict__ sn, u32* __restrict__ maskT){
  int tid  = threadIdx.x;
  int lane = tid & 63;
  int t = __builtin_amdgcn_readfirstlane((int)blockIdx.x*4 + (tid >> 6));  // tile id 0..4159
  // decode t -> k (I-block), bj (J-block): C(k) = k*(129-k)
  int k = (int)((129.0f - sqrtf((float)(16641 - 4*t))) * 0.5f);
  k = k < 0 ? 0 : (k > 63 ? 63 : k);
  while (k*(129-k) > t) --k;
  while ((k+1)*(128-k) <= t) ++k;        // C(k+1) = (k+1)*(129-(k+1))
  int I0 = k << 7;
  int J0 = ((k<<1) + (t - k*(129-k))) << 6;

  float siA[16], siB[16];
  #pragma unroll
  for (int q=0;q<4;q++){
    float4 a = reinterpret_cast<const float4*>(sn + (I0+lane)*16)[q];
    float4 b = reinterpret_cast<const float4*>(sn + (I0+64+lane)*16)[q];
    siA[4*q]=a.x; siA[4*q+1]=a.y; siA[4*q+2]=a.z; siA[4*q+3]=a.w;
    siB[4*q]=b.x; siB[4*q+1]=b.y; siB[4*q+2]=b.z; siB[4*q+3]=b.w;
  }

  u32 wA0=0, wA1=0, wB0=0, wB1=0;        // row-words: rows iA,iB over 64 j-bits
  u32 cAlo=0, cAhi=0, cBlo=0, cBhi=0;    // col-words: row j=J0+lane over 128 i-bits
  #pragma unroll
  for (int jh=0; jh<2; ++jh){
    u32 wa = 0, wb = 0;
    #pragma unroll 4
    for (int j2=0; j2<32; ++j2){
      int jl = jh*32 + j2;
      const float* sp = sn + (J0 + jl)*16;           // wave-uniform -> s_load
      float dA0 = sp[0] *siA[0]  + sp[1] *siA[1]  + sp[2] *siA[2]  + sp[3] *siA[3];
      float dA1 = sp[4] *siA[4]  + sp[5] *siA[5]  + sp[6] *siA[6]  + sp[7] *siA[7];
      float dA2 = sp[8] *siA[8]  + sp[9] *siA[9]  + sp[10]*siA[10] + sp[11]*siA[11];
      float dA3 = sp[12]*siA[12] + sp[13]*siA[13] + sp[14]*siA[14] + sp[15]*siA[15];
      float dB0 = sp[0] *siB[0]  + sp[1] *siB[1]  + sp[2] *siB[2]  + sp[3] *siB[3];
      float dB1 = sp[4] *siB[4]  + sp[5] *siB[5]  + sp[6] *siB[6]  + sp[7] *siB[7];
      float dB2 = sp[8] *siB[8]  + sp[9] *siB[9]  + sp[10]*siB[10] + sp[11]*siB[11];
      float dB3 = sp[12]*siB[12] + sp[13]*siB[13] + sp[14]*siB[14] + sp[15]*siB[15];
      float dA = (dA0+dA1)+(dA2+dA3);
      float dB = (dB0+dB1)+(dB2+dB3);
      bool pA = (dA*dA >= THRESH);
      bool pB = (dB*dB >= THRESH);
      u64 balA = __ballot(pA);
      u64 balB = __ballot(pB);
      wa |= pA ? (1u<<j2) : 0u;
      wb |= pB ? (1u<<j2) : 0u;
      bool me = (lane == jl);
      cAlo = me ? (u32)balA        : cAlo;
      cAhi = me ? (u32)(balA>>32)  : cAhi;
      cBlo = me ? (u32)balB        : cBlo;
      cBhi = me ? (u32)(balB>>32)  : cBhi;
    }
    if (jh==0){ wA0=wa; wB0=wb; } else { wA1=wa; wB1=wb; }
  }

  // self-loop clearing (diagonal-intersecting tiles only; J0>=I0 always)
  if (J0 == I0){
    if (lane < 32){ wA0 &= ~(1u<<lane); cAlo &= ~(1u<<lane); }
    else          { wA1 &= ~(1u<<(lane-32)); cAhi &= ~(1u<<(lane-32)); }
  }
  if (J0 == I0 + 64){
    if (lane < 32){ wB0 &= ~(1u<<lane); cBlo &= ~(1u<<lane); }
    else          { wB1 &= ~(1u<<(lane-32)); cBhi &= ~(1u<<(lane-32)); }
  }

  int iA = I0 + lane, iB = iA + 64, jg = J0 + lane;
  size_t jw = (size_t)(J0>>5)*NN;
  size_t iw = (size_t)(I0>>5)*NN;
  maskT[jw      + iA] = wA0;  maskT[jw + NN + iA] = wA1;
  maskT[jw      + iB] = wB0;  maskT[jw + NN + iB] = wB1;
  maskT[iw        + jg] = cAlo; maskT[iw +   NN + jg] = cAhi;
  maskT[iw + 2*NN + jg] = cBlo; maskT[iw + 3*NN + jg] = cBhi;
}

// ---- K2b: deg[i] = popcount of mask row i; dinv = 1/(deg+eps) ----
__global__ __launch_bounds__(256) void k_deg(const u32* __restrict__ maskT, float* __restrict__ dinvF){
  __shared__ u32 red[256];
  int tid = threadIdx.x;
  int il = tid & 31, ws = tid >> 5;
  int i = blockIdx.x*32 + il;                    // 256 blocks
  u32 s = 0;
  #pragma unroll 8
  for (int w = ws*32; w < ws*32 + 32; ++w) s += __popc(maskT[(size_t)w*NN + i]);
  red[tid] = s;
  __syncthreads();
  if (tid < 32){
    u32 tot = 0;
    #pragma unroll
    for (int g=0; g<8; ++g) tot += red[g*32 + tid];
    dinvF[i] = 1.0f/((float)tot + 1e-6f);
  }
}

// ---- K3: Yt[f][j] = dinv[j] * sum_k X[j,k]*W[f,k]   (bf16, j-contiguous) ----
__global__ __launch_bounds__(128) void k_ygemm(const float* __restrict__ X, const float* __restrict__ W,
                                               const float* __restrict__ dinvF, u16* __restrict__ Yt){
  int tid = threadIdx.x;
  int lane = tid & 63;
  int r = lane & 15, g = lane >> 4;
  int wj = tid >> 6;
  int f0 = blockIdx.x * 32;
  int j0 = blockIdx.y * 128 + wj * 64;
  f32x4 acc[2][4] = {};
  #pragma unroll
  for (int k0 = 0; k0 < 256; k0 += 32){
    short8 a[2], b[4];
    #pragma unroll
    for (int af=0; af<2; af++){
      const float* p = W + (f0 + af*16 + r)*256 + k0 + g*8;
      float4 u = reinterpret_cast<const float4*>(p)[0];
      float4 v = reinterpret_cast<const float4*>(p)[1];
      short8 t;
      t[0]=(short)f2bf(u.x); t[1]=(short)f2bf(u.y); t[2]=(short)f2bf(u.z); t[3]=(short)f2bf(u.w);
      t[4]=(short)f2bf(v.x); t[5]=(short)f2bf(v.y); t[6]=(short)f2bf(v.z); t[7]=(short)f2bf(v.w);
      a[af] = t;
    }
    #pragma unroll
    for (int bf=0; bf<4; bf++){
      const float* p = X + (j0 + bf*16 + r)*256 + k0 + g*8;
      float4 u = reinterpret_cast<const float4*>(p)[0];
      float4 v = reinterpret_cast<const float4*>(p)[1];
      short8 t;
      t[0]=(short)f2bf(u.x); t[1]=(short)f2bf(u.y); t[2]=(short)f2bf(u.z); t[3]=(short)f2bf(u.w);
      t[4]=(short)f2bf(v.x); t[5]=(short)f2bf(v.y); t[6]=(short)f2bf(v.z); t[7]=(short)f2bf(v.w);
      b[bf] = t;
    }
    #pragma unroll
    for (int af=0; af<2; af++)
      #pragma unroll
      for (int bf=0; bf<4; bf++)
        acc[af][bf] = __builtin_amdgcn_mfma_f32_16x16x32_bf16(a[af], b[bf], acc[af][bf], 0, 0, 0);
  }
  float ds[4];
  #pragma unroll
  for (int bf=0;bf<4;bf++) ds[bf] = dinvF[j0 + bf*16 + r];
  #pragma unroll
  for (int af=0; af<2; af++)
    #pragma unroll
    for (int bf=0; bf<4; bf++)
      #pragma unroll
      for (int q=0;q<4;q++)
        Yt[(f0 + af*16 + g*4 + q)*NN + j0 + bf*16 + r] = f2bf(acc[af][bf][q] * ds[bf]);
}

// ---- K4: partial[z] = M[m-tile, k-slice] @ Yt^T  (mask bits -> bf16 A in regs) ----
__global__ __launch_bounds__(256) void k_agg(const u16* __restrict__ Yt, const u32* __restrict__ maskT,
                                             float* __restrict__ part){
  __shared__ u8  ldsB[128*128];   // B tile [n-local 128][k 64] bf16, chunk-XOR swizzled
  __shared__ u32 ldsM[2][128];    // mask words (k0..k0+63) for 128 m-rows
  int tid = threadIdx.x;
  int lane = tid & 63, wid = tid >> 6;
  int r = lane & 15, g = lane >> 4;
  int wm = wid >> 1, wn = wid & 1;
  int m0 = blockIdx.x*128, n0 = blockIdx.y*128;
  int kbase = blockIdx.z*2048;
  f32x4 acc[4][4] = {};
  int srow = tid >> 1, shalf = tid & 1;
  for (int ks = 0; ks < 2048; ks += 64){
    int k0 = kbase + ks;
    #pragma unroll
    for (int cc=0; cc<4; cc++){
      int chunk = shalf*4 + cc;
      short8 v = *reinterpret_cast<const short8*>(Yt + (n0+srow)*NN + k0 + chunk*8);
      *reinterpret_cast<short8*>(ldsB + srow*128 + ((chunk ^ (srow&7))<<4)) = v;
    }
    ldsM[tid>>7][tid&127] = maskT[(size_t)((k0>>5) + (tid>>7))*NN + m0 + (tid&127)];
    __syncthreads();
    #pragma unroll
    for (int kk=0; kk<2; kk++){
      short8 bfrag[4];
      #pragma unroll
      for (int nf=0; nf<4; nf++){
        int row = wn*64 + nf*16 + r;
        int chunk = kk*4 + g;
        bfrag[nf] = *reinterpret_cast<const short8*>(ldsB + row*128 + ((chunk ^ (row&7))<<4));
      }
      #pragma unroll
      for (int mf=0; mf<4; mf++){
        u32 mb = (ldsM[kk][wm*64 + mf*16 + r] >> (g*8)) & 0xffu;
        short8 a;
        #pragma unroll
        for (int e=0;e<8;e++) a[e] = (short)(((mb >> e) & 1u) ? 0x3F80 : 0);  // bf16 1.0 / 0
        #pragma unroll
        for (int nf=0; nf<4; nf++)
          acc[mf][nf] = __builtin_amdgcn_mfma_f32_16x16x32_bf16(a, bfrag[nf], acc[mf][nf], 0, 0, 0);
      }
    }
    __syncthreads();
  }
  float* dst = part + (size_t)blockIdx.z * (NN*256);
  #pragma unroll
  for (int mf=0; mf<4; mf++)
    #pragma unroll
    for (int nf=0; nf<4; nf++)
      #pragma unroll
      for (int q=0;q<4;q++){
        int row = m0 + wm*64 + mf*16 + g*4 + q;
        int col = n0 + wn*64 + nf*16 + r;
        dst[row*256 + col] = acc[mf][nf][q];
      }
}

// ---- K5: out = bias + sum_z partial[z] ----
__global__ __launch_bounds__(256) void k_reduce(const float* __restrict__ part, const float* __restrict__ bias,
                                                float* __restrict__ out){
  int i = blockIdx.x*256 + threadIdx.x;          // float4 index; grid exactly covers 524288
  float4 s0 = reinterpret_cast<const float4*>(part          )[i];
  float4 s1 = reinterpret_cast<const float4*>(part + 2097152)[i];
  float4 s2 = reinterpret_cast<const float4*>(part + 4194304)[i];
  float4 s3 = reinterpret_cast<const float4*>(part + 6291456)[i];
  float4 bb = reinterpret_cast<const float4*>(bias)[i & 63];
  float4 o;
  o.x = s0.x+s1.x+s2.x+s3.x+bb.x;
  o.y = s0.y+s1.y+s2.y+s3.y+bb.y;
  o.z = s0.z+s1.z+s2.z+s3.z+bb.z;
  o.w = s0.w+s1.w+s2.w+s3.w+bb.w;
  reinterpret_cast<float4*>(out)[i] = o;
}

extern "C" void kernel_launch(void* const* d_in, const int* in_sizes, int n_in,
                              void* d_out, int out_size, void* d_ws, size_t ws_size,
                              hipStream_t stream) {
  const float* X    = (const float*)d_in[0];   // node_features [8192,256]
  const float* S    = (const float*)d_in[1];   // states        [8192,16]
  const float* W    = (const float*)d_in[2];   // W             [256,256]
  const float* bias = (const float*)d_in[3];   // b             [256]
  float* out = (float*)d_out;
  char* ws = (char*)d_ws;
  // workspace layout (bytes)
  u32*   maskT = (u32*)  (ws + 0);         //  8 MiB  bitmask transposed [256 words][8192 i]
  u16*   Yt    = (u16*)  (ws + 8388608);   //  4 MiB  bf16 [256][8192] = (deg_inv*X@W^T)^T
  float* snorm = (float*)(ws + 12582912);  // 512 KiB normalized states
  float* dinvF = (float*)(ws + 13107200);  //  32 KiB
  float* part  = (float*)(ws + 13139968);  //  32 MiB fp32 partials [4][8192][256]

  k_norm  <<<dim3(32),        dim3(256), 0, stream>>>(S, snorm);
  k_maskT2<<<dim3(1040),      dim3(256), 0, stream>>>(snorm, maskT);
  k_deg   <<<dim3(256),       dim3(256), 0, stream>>>(maskT, dinvF);
  k_ygemm <<<dim3(8,64),      dim3(128), 0, stream>>>(X, W, dinvF, Yt);
  k_agg   <<<dim3(64,2,4),    dim3(256), 0, stream>>>(Yt, maskT, part);
  k_reduce<<<dim3(2048),      dim3(256), 0, stream>>>(part, bias, out);
}

// Round 5
// 110.898 us; speedup vs baseline: 2.1021x; 1.0657x over previous
//
#include <hip/hip_runtime.h>
#include <hip/hip_bf16.h>

typedef __attribute__((ext_vector_type(8))) short short8;
typedef __attribute__((ext_vector_type(4))) float f32x4;
typedef __attribute__((ext_vector_type(4))) unsigned int u32x4;
typedef unsigned short u16;
typedef unsigned int   u32;
typedef unsigned long long u64;
typedef unsigned char  u8;

#define NN 8192
#define THRESH 0.1f

__device__ __forceinline__ u16 f2bf(float f){
  __hip_bfloat16 h = __float2bfloat16(f);
  u16 u; __builtin_memcpy(&u, &h, 2); return u;
}

// 8 mask bits -> 8 bf16 (1.0/0.0). Pair trick: ((b>>2p)&3)*0x8001 & 0x10001 -> {bit0@0,bit1@16}; *0x3F80.
__device__ __forceinline__ short8 expand_mask8(u32 byte){
  u32x4 w;
  #pragma unroll
  for (int p=0;p<4;p++){
    u32 t = (((byte >> (2*p)) & 3u) * 0x8001u) & 0x00010001u;
    w[p] = t * 0x3F80u;
  }
  return __builtin_bit_cast(short8, w);
}

// ---- K1: normalize state rows ----
__global__ __launch_bounds__(256) void k_norm(const float* __restrict__ st, float* __restrict__ sn){
  int i = blockIdx.x*256 + threadIdx.x;
  const float4* s4 = reinterpret_cast<const float4*>(st + i*16);
  float4 v[4]; float ss = 0.f;
  #pragma unroll
  for (int q=0;q<4;q++){ v[q]=s4[q]; ss += v[q].x*v[q].x+v[q].y*v[q].y+v[q].z*v[q].z+v[q].w*v[q].w; }
  float inv = 1.0f/(sqrtf(ss) + 1e-12f);
  float4* d4 = reinterpret_cast<float4*>(sn + i*16);
  #pragma unroll
  for (int q=0;q<4;q++){ float4 o; o.x=v[q].x*inv; o.y=v[q].y*inv; o.z=v[q].z*inv; o.w=v[q].w*inv; d4[q]=o; }
}

// ---- K2: symmetric tile mask. Wave = 256 i-rows (4/lane) x 64 j. Upper-tri tiles (J0>=I0).
// Row-words from per-lane predicates; transposed col-words from __ballot. ----
__global__ __launch_bounds__(256) void k_maskT3(const float* __restrict__ sn, u32* __restrict__ maskT){
  int tid  = threadIdx.x;
  int lane = tid & 63;
  int t = __builtin_amdgcn_readfirstlane((int)blockIdx.x*4 + (tid >> 6));  // 0..2111
  // decode: C(k) = 130k - 2k^2 tiles before I-block k (I-blocks of 256, J-blocks of 64)
  int k = 0;
  while (130*(k+1) - 2*(k+1)*(k+1) <= t) ++k;
  int I0 = __builtin_amdgcn_readfirstlane(k << 8);
  int jb = 4*k + (t - (130*k - 2*k*k));
  int J0 = __builtin_amdgcn_readfirstlane(jb << 6);

  float si[4][16];
  #pragma unroll
  for (int c=0;c<4;c++){
    #pragma unroll
    for (int q=0;q<4;q++){
      float4 v = reinterpret_cast<const float4*>(sn + (I0 + 64*c + lane)*16)[q];
      si[c][4*q]=v.x; si[c][4*q+1]=v.y; si[c][4*q+2]=v.z; si[c][4*q+3]=v.w;
    }
  }

  u32 roww[4][2]; u32 colw[8];
  #pragma unroll
  for (int c=0;c<4;c++){ roww[c][0]=0u; roww[c][1]=0u; }
  #pragma unroll
  for (int w=0;w<8;w++) colw[w]=0u;

  #pragma unroll
  for (int jh=0; jh<2; ++jh){
    #pragma unroll 2
    for (int j2=0; j2<32; ++j2){
      int jl = jh*32 + j2;
      const float* sp = sn + (J0 + jl)*16;           // wave-uniform -> scalar loads
      bool pr[4]; u64 bal[4];
      #pragma unroll
      for (int c=0;c<4;c++){
        float d0 = sp[0] *si[c][0]  + sp[1] *si[c][1]  + sp[2] *si[c][2]  + sp[3] *si[c][3];
        float d1 = sp[4] *si[c][4]  + sp[5] *si[c][5]  + sp[6] *si[c][6]  + sp[7] *si[c][7];
        float d2 = sp[8] *si[c][8]  + sp[9] *si[c][9]  + sp[10]*si[c][10] + sp[11]*si[c][11];
        float d3 = sp[12]*si[c][12] + sp[13]*si[c][13] + sp[14]*si[c][14] + sp[15]*si[c][15];
        float d  = (d0+d1)+(d2+d3);
        pr[c] = (d*d >= THRESH);
        bal[c] = __ballot(pr[c]);
        roww[c][jh] |= pr[c] ? (1u<<j2) : 0u;
      }
      bool me = (lane == jl);
      #pragma unroll
      for (int c=0;c<4;c++){
        colw[2*c]   = me ? (u32)bal[c]        : colw[2*c];
        colw[2*c+1] = me ? (u32)(bal[c]>>32)  : colw[2*c+1];
      }
    }
  }

  // self-loop clearing
  #pragma unroll
  for (int c=0;c<4;c++){
    u32 rel = (u32)(I0 + 64*c + lane - J0);
    if (rel < 64u) roww[c][rel>>5] &= ~(1u<<(rel&31));
  }
  int jg = J0 + lane;
  u32 off = (u32)(jg - I0);
  if (off < 256u) colw[off>>5] &= ~(1u<<(off&31));

  #pragma unroll
  for (int c=0;c<4;c++){
    int i = I0 + 64*c + lane;
    maskT[(size_t)((J0>>5)  )*NN + i] = roww[c][0];
    maskT[(size_t)((J0>>5)+1)*NN + i] = roww[c][1];
  }
  #pragma unroll
  for (int w=0;w<8;w++)
    maskT[(size_t)((I0>>5)+w)*NN + jg] = colw[w];
}

// ---- K2b: deg[i] via popcount; dinv = 1/(deg+eps) ----
__global__ __launch_bounds__(256) void k_deg(const u32* __restrict__ maskT, float* __restrict__ dinvF){
  __shared__ u32 red[256];
  int tid = threadIdx.x;
  int il = tid & 31, ws = tid >> 5;
  int i = blockIdx.x*32 + il;
  u32 s = 0;
  #pragma unroll 8
  for (int w = ws*32; w < ws*32 + 32; ++w) s += __popc(maskT[(size_t)w*NN + i]);
  red[tid] = s;
  __syncthreads();
  if (tid < 32){
    u32 tot = 0;
    #pragma unroll
    for (int g=0; g<8; ++g) tot += red[g*32 + tid];
    dinvF[i] = 1.0f/((float)tot + 1e-6f);
  }
}

// ---- K3: Yt[f][j] = dinv[j] * sum_k X[j,k]*W[f,k]  (bf16, j-contiguous) ----
__global__ __launch_bounds__(128) void k_ygemm(const float* __restrict__ X, const float* __restrict__ W,
                                               const float* __restrict__ dinvF, u16* __restrict__ Yt){
  int tid = threadIdx.x;
  int lane = tid & 63;
  int r = lane & 15, g = lane >> 4;
  int wj = tid >> 6;
  int f0 = blockIdx.x * 32;
  int j0 = blockIdx.y * 128 + wj * 64;
  f32x4 acc[2][4] = {};
  #pragma unroll
  for (int k0 = 0; k0 < 256; k0 += 32){
    short8 a[2], b[4];
    #pragma unroll
    for (int af=0; af<2; af++){
      const float* p = W + (f0 + af*16 + r)*256 + k0 + g*8;
      float4 u = reinterpret_cast<const float4*>(p)[0];
      float4 v = reinterpret_cast<const float4*>(p)[1];
      short8 tt;
      tt[0]=(short)f2bf(u.x); tt[1]=(short)f2bf(u.y); tt[2]=(short)f2bf(u.z); tt[3]=(short)f2bf(u.w);
      tt[4]=(short)f2bf(v.x); tt[5]=(short)f2bf(v.y); tt[6]=(short)f2bf(v.z); tt[7]=(short)f2bf(v.w);
      a[af] = tt;
    }
    #pragma unroll
    for (int bf=0; bf<4; bf++){
      const float* p = X + (j0 + bf*16 + r)*256 + k0 + g*8;
      float4 u = reinterpret_cast<const float4*>(p)[0];
      float4 v = reinterpret_cast<const float4*>(p)[1];
      short8 tt;
      tt[0]=(short)f2bf(u.x); tt[1]=(short)f2bf(u.y); tt[2]=(short)f2bf(u.z); tt[3]=(short)f2bf(u.w);
      tt[4]=(short)f2bf(v.x); tt[5]=(short)f2bf(v.y); tt[6]=(short)f2bf(v.z); tt[7]=(short)f2bf(v.w);
      b[bf] = tt;
    }
    #pragma unroll
    for (int af=0; af<2; af++)
      #pragma unroll
      for (int bf=0; bf<4; bf++)
        acc[af][bf] = __builtin_amdgcn_mfma_f32_16x16x32_bf16(a[af], b[bf], acc[af][bf], 0, 0, 0);
  }
  float ds[4];
  #pragma unroll
  for (int bf=0;bf<4;bf++) ds[bf] = dinvF[j0 + bf*16 + r];
  #pragma unroll
  for (int af=0; af<2; af++)
    #pragma unroll
    for (int bf=0; bf<4; bf++)
      #pragma unroll
      for (int q=0;q<4;q++)
        Yt[(f0 + af*16 + g*4 + q)*NN + j0 + bf*16 + r] = f2bf(acc[af][bf][q] * ds[bf]);
}

// ---- K4: partial[z] = M @ Y  via 2-phase global_load_lds prefetch + in-reg mask expansion.
// RACE FIX (R4->R5): __syncthreads()'s fence was not draining the async global_load_lds
// (LDS-DMA) ops issued a phase earlier -> stale-tile reads under replay timing. Explicit
// s_waitcnt vmcnt(0) before EVERY barrier guarantees the staged tile has landed. ----
#define VMCNT0 asm volatile("s_waitcnt vmcnt(0)" ::: "memory")
__global__ __launch_bounds__(256) void k_agg(const u16* __restrict__ Yt, const u32* __restrict__ maskT,
                                             float* __restrict__ part){
  __shared__ u8  ldsB[2][16384];  // [buf][128 n-rows][64 k] bf16, chunk-XOR swizzled via source
  __shared__ u32 ldsM[2][2][128]; // [buf][kword][m-row]
  int tid = threadIdx.x;
  int lane = tid & 63, wid = tid >> 6;
  int r = lane & 15, g = lane >> 4;
  int wm = wid >> 1, wn = wid & 1;
  // XCD swizzle: 8 groups (n0,zz) x 64 m-blocks; p%8 keeps each (n0,zz) on one XCD.
  int p = (int)blockIdx.x + 64*((int)blockIdx.y + 2*(int)blockIdx.z);
  int gq = p & 7, idx = p >> 3;
  int m0 = idx*128;
  int n0 = (gq & 1)*128;
  int zz = gq >> 1;
  int kbase = zz*2048;
  int mrow = tid >> 7, mcol = tid & 127;
  f32x4 acc[4][4] = {};
  u32 mreg;

#define GSTAGE(BUF, T) do { \
    _Pragma("unroll") \
    for (int is=0; is<4; ++is){ \
      int rw = wid*32 + is*8 + (lane>>3); \
      const u16* gsrc = Yt + ((size_t)(n0+rw) << 13) + (size_t)(kbase + (T)*64 + (((lane&7) ^ (rw&7))<<3)); \
      __builtin_amdgcn_global_load_lds((const __attribute__((address_space(1))) void*)gsrc, \
          (__attribute__((address_space(3))) void*)&ldsB[BUF][wid*4096 + is*1024], 16, 0, 0); \
    } \
  } while(0)

#define MLOAD(T)    mreg = maskT[(size_t)((kbase>>5) + 2*(T) + mrow)*NN + m0 + mcol]
#define MSTORE(BUF) ldsM[BUF][mrow][mcol] = mreg

#define COMPUTE(BUF) do { \
    _Pragma("unroll") \
    for (int kk=0; kk<2; ++kk){ \
      short8 bfrag[4]; \
      _Pragma("unroll") \
      for (int nf=0; nf<4; ++nf){ \
        int row = wn*64 + nf*16 + r; \
        int chunk = kk*4 + g; \
        bfrag[nf] = *reinterpret_cast<const short8*>(&ldsB[BUF][row*128 + ((chunk ^ (row&7))<<4)]); \
      } \
      _Pragma("unroll") \
      for (int mf=0; mf<4; ++mf){ \
        u32 mw = ldsM[BUF][kk][wm*64 + mf*16 + r]; \
        short8 a = expand_mask8((mw >> (g*8)) & 0xffu); \
        _Pragma("unroll") \
        for (int nf=0; nf<4; ++nf) \
          acc[mf][nf] = __builtin_amdgcn_mfma_f32_16x16x32_bf16(a, bfrag[nf], acc[mf][nf], 0, 0, 0); \
      } \
    } \
  } while(0)

  GSTAGE(0, 0); MLOAD(0); MSTORE(0);
  VMCNT0;
  __syncthreads();
  #pragma unroll 1
  for (int t = 0; t < 30; t += 2){
    GSTAGE(1, t+1); MLOAD(t+1);
    COMPUTE(0);
    MSTORE(1);
    VMCNT0;
    __syncthreads();
    GSTAGE(0, t+2); MLOAD(t+2);
    COMPUTE(1);
    MSTORE(0);
    VMCNT0;
    __syncthreads();
  }
  GSTAGE(1, 31); MLOAD(31);
  COMPUTE(0);
  MSTORE(1);
  VMCNT0;
  __syncthreads();
  COMPUTE(1);

#undef GSTAGE
#undef MLOAD
#undef MSTORE
#undef COMPUTE

  float* dst = part + (size_t)zz * (NN*256);
  #pragma unroll
  for (int mf=0; mf<4; mf++)
    #pragma unroll
    for (int nf=0; nf<4; nf++)
      #pragma unroll
      for (int q=0;q<4;q++){
        int row = m0 + wm*64 + mf*16 + g*4 + q;
        int col = n0 + wn*64 + nf*16 + r;
        dst[row*256 + col] = acc[mf][nf][q];
      }
}

// ---- K5: out = bias + sum_z partial[z] ----
__global__ __launch_bounds__(256) void k_reduce(const float* __restrict__ part, const float* __restrict__ bias,
                                                float* __restrict__ out){
  int i = blockIdx.x*256 + threadIdx.x;
  float4 s0 = reinterpret_cast<const float4*>(part          )[i];
  float4 s1 = reinterpret_cast<const float4*>(part + 2097152)[i];
  float4 s2 = reinterpret_cast<const float4*>(part + 4194304)[i];
  float4 s3 = reinterpret_cast<const float4*>(part + 6291456)[i];
  float4 bb = reinterpret_cast<const float4*>(bias)[i & 63];
  float4 o;
  o.x = s0.x+s1.x+s2.x+s3.x+bb.x;
  o.y = s0.y+s1.y+s2.y+s3.y+bb.y;
  o.z = s0.z+s1.z+s2.z+s3.z+bb.z;
  o.w = s0.w+s1.w+s2.w+s3.w+bb.w;
  reinterpret_cast<float4*>(out)[i] = o;
}

extern "C" void kernel_launch(void* const* d_in, const int* in_sizes, int n_in,
                              void* d_out, int out_size, void* d_ws, size_t ws_size,
                              hipStream_t stream) {
  const float* X    = (const float*)d_in[0];
  const float* S    = (const float*)d_in[1];
  const float* W    = (const float*)d_in[2];
  const float* bias = (const float*)d_in[3];
  float* out = (float*)d_out;
  char* ws = (char*)d_ws;
  u32*   maskT = (u32*)  (ws + 0);         //  8 MiB  [256 jwords][8192 i]
  u16*   Yt    = (u16*)  (ws + 8388608);   //  4 MiB  bf16 [256 f][8192 j]
  float* snorm = (float*)(ws + 12582912);  // 512 KiB
  float* dinvF = (float*)(ws + 13107200);  //  32 KiB
  float* part  = (float*)(ws + 13139968);  //  32 MiB fp32 [4][8192][256]

  k_norm  <<<dim3(32),     dim3(256), 0, stream>>>(S, snorm);
  k_maskT3<<<dim3(528),    dim3(256), 0, stream>>>(snorm, maskT);
  k_deg   <<<dim3(256),    dim3(256), 0, stream>>>(maskT, dinvF);
  k_ygemm <<<dim3(8,64),   dim3(128), 0, stream>>>(X, W, dinvF, Yt);
  k_agg   <<<dim3(64,2,4), dim3(256), 0, stream>>>(Yt, maskT, part);
  k_reduce<<<dim3(2048),   dim3(256), 0, stream>>>(part, bias, out);
}

// Round 6
// 105.239 us; speedup vs baseline: 2.2151x; 1.0538x over previous
//
#include <hip/hip_runtime.h>
#include <hip/hip_bf16.h>

typedef __attribute__((ext_vector_type(8))) short short8;
typedef __attribute__((ext_vector_type(4))) float f32x4;
typedef __attribute__((ext_vector_type(4))) unsigned int u32x4;
typedef unsigned short u16;
typedef unsigned int   u32;
typedef unsigned long long u64;
typedef unsigned char  u8;

#define NN 8192
#define THRESH 0.1f

__device__ __forceinline__ u16 f2bf(float f){
  __hip_bfloat16 h = __float2bfloat16(f);
  u16 u; __builtin_memcpy(&u, &h, 2); return u;
}

// ---- K1: normalize state rows ----
__global__ __launch_bounds__(256) void k_norm(const float* __restrict__ st, float* __restrict__ sn){
  int i = blockIdx.x*256 + threadIdx.x;
  const float4* s4 = reinterpret_cast<const float4*>(st + i*16);
  float4 v[4]; float ss = 0.f;
  #pragma unroll
  for (int q=0;q<4;q++){ v[q]=s4[q]; ss += v[q].x*v[q].x+v[q].y*v[q].y+v[q].z*v[q].z+v[q].w*v[q].w; }
  float inv = 1.0f/(sqrtf(ss) + 1e-12f);
  float4* d4 = reinterpret_cast<float4*>(sn + i*16);
  #pragma unroll
  for (int q=0;q<4;q++){ float4 o; o.x=v[q].x*inv; o.y=v[q].y*inv; o.z=v[q].z*inv; o.w=v[q].w*inv; d4[q]=o; }
}

// ---- K2: symmetric tile mask. Wave = 256 i-rows (4/lane) x 64 j. Upper-tri tiles (J0>=I0). ----
__global__ __launch_bounds__(256) void k_maskT3(const float* __restrict__ sn, u32* __restrict__ maskT){
  int tid  = threadIdx.x;
  int lane = tid & 63;
  int t = __builtin_amdgcn_readfirstlane((int)blockIdx.x*4 + (tid >> 6));  // 0..2111
  int k = 0;
  while (130*(k+1) - 2*(k+1)*(k+1) <= t) ++k;
  int I0 = __builtin_amdgcn_readfirstlane(k << 8);
  int jb = 4*k + (t - (130*k - 2*k*k));
  int J0 = __builtin_amdgcn_readfirstlane(jb << 6);

  float si[4][16];
  #pragma unroll
  for (int c=0;c<4;c++){
    #pragma unroll
    for (int q=0;q<4;q++){
      float4 v = reinterpret_cast<const float4*>(sn + (I0 + 64*c + lane)*16)[q];
      si[c][4*q]=v.x; si[c][4*q+1]=v.y; si[c][4*q+2]=v.z; si[c][4*q+3]=v.w;
    }
  }

  u32 roww[4][2]; u32 colw[8];
  #pragma unroll
  for (int c=0;c<4;c++){ roww[c][0]=0u; roww[c][1]=0u; }
  #pragma unroll
  for (int w=0;w<8;w++) colw[w]=0u;

  #pragma unroll
  for (int jh=0; jh<2; ++jh){
    #pragma unroll 2
    for (int j2=0; j2<32; ++j2){
      int jl = jh*32 + j2;
      const float* sp = sn + (J0 + jl)*16;           // wave-uniform -> scalar loads
      bool pr[4]; u64 bal[4];
      #pragma unroll
      for (int c=0;c<4;c++){
        float d0 = sp[0] *si[c][0]  + sp[1] *si[c][1]  + sp[2] *si[c][2]  + sp[3] *si[c][3];
        float d1 = sp[4] *si[c][4]  + sp[5] *si[c][5]  + sp[6] *si[c][6]  + sp[7] *si[c][7];
        float d2 = sp[8] *si[c][8]  + sp[9] *si[c][9]  + sp[10]*si[c][10] + sp[11]*si[c][11];
        float d3 = sp[12]*si[c][12] + sp[13]*si[c][13] + sp[14]*si[c][14] + sp[15]*si[c][15];
        float d  = (d0+d1)+(d2+d3);
        pr[c] = (d*d >= THRESH);
        bal[c] = __ballot(pr[c]);
        roww[c][jh] |= pr[c] ? (1u<<j2) : 0u;
      }
      bool me = (lane == jl);
      #pragma unroll
      for (int c=0;c<4;c++){
        colw[2*c]   = me ? (u32)bal[c]        : colw[2*c];
        colw[2*c+1] = me ? (u32)(bal[c]>>32)  : colw[2*c+1];
      }
    }
  }

  #pragma unroll
  for (int c=0;c<4;c++){
    u32 rel = (u32)(I0 + 64*c + lane - J0);
    if (rel < 64u) roww[c][rel>>5] &= ~(1u<<(rel&31));
  }
  int jg = J0 + lane;
  u32 off = (u32)(jg - I0);
  if (off < 256u) colw[off>>5] &= ~(1u<<(off&31));

  #pragma unroll
  for (int c=0;c<4;c++){
    int i = I0 + 64*c + lane;
    maskT[(size_t)((J0>>5)  )*NN + i] = roww[c][0];
    maskT[(size_t)((J0>>5)+1)*NN + i] = roww[c][1];
  }
  #pragma unroll
  for (int w=0;w<8;w++)
    maskT[(size_t)((I0>>5)+w)*NN + jg] = colw[w];
}

// ---- K2b: deg[i] via popcount; dinv = 1/(deg+eps) ----
__global__ __launch_bounds__(256) void k_deg(const u32* __restrict__ maskT, float* __restrict__ dinvF){
  __shared__ u32 red[256];
  int tid = threadIdx.x;
  int il = tid & 31, ws = tid >> 5;
  int i = blockIdx.x*32 + il;
  u32 s = 0;
  #pragma unroll 8
  for (int w = ws*32; w < ws*32 + 32; ++w) s += __popc(maskT[(size_t)w*NN + i]);
  red[tid] = s;
  __syncthreads();
  if (tid < 32){
    u32 tot = 0;
    #pragma unroll
    for (int g=0; g<8; ++g) tot += red[g*32 + tid];
    dinvF[i] = 1.0f/((float)tot + 1e-6f);
  }
}

// ---- K3: Yt[f][j] = dinv[j] * sum_k X[j,k]*W[f,k]  (bf16, j-contiguous) ----
__global__ __launch_bounds__(128) void k_ygemm(const float* __restrict__ X, const float* __restrict__ W,
                                               const float* __restrict__ dinvF, u16* __restrict__ Yt){
  int tid = threadIdx.x;
  int lane = tid & 63;
  int r = lane & 15, g = lane >> 4;
  int wj = tid >> 6;
  int f0 = blockIdx.x * 32;
  int j0 = blockIdx.y * 128 + wj * 64;
  f32x4 acc[2][4] = {};
  #pragma unroll
  for (int k0 = 0; k0 < 256; k0 += 32){
    short8 a[2], b[4];
    #pragma unroll
    for (int af=0; af<2; af++){
      const float* p = W + (f0 + af*16 + r)*256 + k0 + g*8;
      float4 u = reinterpret_cast<const float4*>(p)[0];
      float4 v = reinterpret_cast<const float4*>(p)[1];
      short8 tt;
      tt[0]=(short)f2bf(u.x); tt[1]=(short)f2bf(u.y); tt[2]=(short)f2bf(u.z); tt[3]=(short)f2bf(u.w);
      tt[4]=(short)f2bf(v.x); tt[5]=(short)f2bf(v.y); tt[6]=(short)f2bf(v.z); tt[7]=(short)f2bf(v.w);
      a[af] = tt;
    }
    #pragma unroll
    for (int bf=0; bf<4; bf++){
      const float* p = X + (j0 + bf*16 + r)*256 + k0 + g*8;
      float4 u = reinterpret_cast<const float4*>(p)[0];
      float4 v = reinterpret_cast<const float4*>(p)[1];
      short8 tt;
      tt[0]=(short)f2bf(u.x); tt[1]=(short)f2bf(u.y); tt[2]=(short)f2bf(u.z); tt[3]=(short)f2bf(u.w);
      tt[4]=(short)f2bf(v.x); tt[5]=(short)f2bf(v.y); tt[6]=(short)f2bf(v.z); tt[7]=(short)f2bf(v.w);
      b[bf] = tt;
    }
    #pragma unroll
    for (int af=0; af<2; af++)
      #pragma unroll
      for (int bf=0; bf<4; bf++)
        acc[af][bf] = __builtin_amdgcn_mfma_f32_16x16x32_bf16(a[af], b[bf], acc[af][bf], 0, 0, 0);
  }
  float ds[4];
  #pragma unroll
  for (int bf=0;bf<4;bf++) ds[bf] = dinvF[j0 + bf*16 + r];
  #pragma unroll
  for (int af=0; af<2; af++)
    #pragma unroll
    for (int bf=0; bf<4; bf++)
      #pragma unroll
      for (int q=0;q<4;q++)
        Yt[(f0 + af*16 + g*4 + q)*NN + j0 + bf*16 + r] = f2bf(acc[af][bf][q] * ds[bf]);
}

// ---- K4: partial[z] = M @ Y. 4-buffer depth-2 global_load_lds pipeline, counted vmcnt
// (never drain to 0 in-loop; R5 proved __syncthreads does NOT drain LDS-DMA, so the
// counted asm wait is the ONLY wait). Mask expansion: 12 VALU/byte bit-smear. ----
#define VMCNT(N) asm volatile("s_waitcnt vmcnt(" #N ")" ::: "memory")
__global__ __launch_bounds__(256) void k_agg(const u16* __restrict__ Yt, const u32* __restrict__ maskT,
                                             float* __restrict__ part){
  __shared__ u8  ldsB[4][16384];  // [buf][128 n-rows][64 k] bf16, chunk-XOR swizzle via source
  __shared__ u32 ldsM[4][256];    // [buf][row*2 + kword]  (DMA lands interleaved)
  int tid = threadIdx.x;
  int lane = tid & 63, wid = tid >> 6;
  int r = lane & 15, g = lane >> 4;
  int wm = wid >> 1, wn = wid & 1;
  // XCD swizzle: 8 groups (n0,zz) x 64 m-blocks; p%8 pins each (n0,zz) group to one XCD.
  int p = (int)blockIdx.x + 64*((int)blockIdx.y + 2*(int)blockIdx.z);
  int gq = p & 7, idx = p >> 3;
  int m0 = idx*128;
  int n0 = (gq & 1)*128;
  int zz = gq >> 1;
  int kbase = zz*2048;
  f32x4 acc[4][4] = {};

  // per-lane global base addresses at step t=0
  const char* ytb[4];
  #pragma unroll
  for (int is=0; is<4; ++is){
    int rw = wid*32 + is*8 + (lane>>3);
    ytb[is] = (const char*)(Yt + ((size_t)(n0+rw) << 13) + (size_t)kbase + (size_t)(((lane&7) ^ (rw&7))<<3));
  }
  const char* mkb = (const char*)(maskT + (size_t)((kbase>>5) + (lane&1))*NN + m0 + wid*32 + (lane>>1));

#define GSTAGE(BUF, T) do { \
    _Pragma("unroll") \
    for (int is=0; is<4; ++is) \
      __builtin_amdgcn_global_load_lds((const __attribute__((address_space(1))) void*)(ytb[is] + (T)*128), \
          (__attribute__((address_space(3))) void*)&ldsB[BUF][wid*4096 + is*1024], 16, 0, 0); \
    __builtin_amdgcn_global_load_lds((const __attribute__((address_space(1))) void*)(mkb + (T)*65536), \
        (__attribute__((address_space(3))) void*)&ldsM[BUF][wid*64], 4, 0, 0); \
  } while(0)

#define COMPUTE(BUF) do { \
    short8 bfrag[2][4]; \
    _Pragma("unroll") \
    for (int kk=0; kk<2; ++kk) \
      _Pragma("unroll") \
      for (int nf=0; nf<4; ++nf) \
        bfrag[kk][nf] = *reinterpret_cast<const short8*>(&ldsB[BUF][(wn*64+nf*16+r)*128 + (((kk*4+g)^(r&7))<<4)]); \
    __builtin_amdgcn_s_setprio(1); \
    _Pragma("unroll") \
    for (int mf=0; mf<4; ++mf){ \
      u64 mw = *reinterpret_cast<const u64*>(&ldsM[BUF][(wm*64+mf*16+r)*2]); \
      _Pragma("unroll") \
      for (int kk=0; kk<2; ++kk){ \
        u32 byte = ((u32)(mw >> (kk*32)) >> (g*8)) & 0xffu; \
        u32 x = byte * 0x8001u; \
        u32x4 wv; \
        _Pragma("unroll") \
        for (int pp=0; pp<4; ++pp) wv[pp] = ((x >> (2*pp)) & 0x00010001u) * 0x3F80u; \
        short8 a = __builtin_bit_cast(short8, wv); \
        _Pragma("unroll") \
        for (int nf=0; nf<4; ++nf) \
          acc[mf][nf] = __builtin_amdgcn_mfma_f32_16x16x32_bf16(a, bfrag[kk][nf], acc[mf][nf], 0, 0, 0); \
      } \
    } \
    __builtin_amdgcn_s_setprio(0); \
  } while(0)

#define BODY(CB, SB, T) do { \
    GSTAGE(SB, (T)+2); \
    COMPUTE(CB); \
    VMCNT(5); \
    __builtin_amdgcn_s_barrier(); \
  } while(0)

  // prologue: stage t=0,1
  GSTAGE(0, 0);
  GSTAGE(1, 1);
  VMCNT(5);                       // stage(0) landed; stage(1) in flight
  __builtin_amdgcn_s_barrier();

  #pragma unroll 1
  for (int t = 0; t < 28; t += 4){
    BODY(0, 2, t);
    BODY(1, 3, t+1);
    BODY(2, 0, t+2);
    BODY(3, 1, t+3);
  }
  BODY(0, 2, 28);                 // stages T=30
  BODY(1, 3, 29);                 // stages T=31
  COMPUTE(2);
  VMCNT(0);                       // stage(31) fully landed (per-wave)
  __builtin_amdgcn_s_barrier();   // ...and cross-wave
  COMPUTE(3);

#undef GSTAGE
#undef COMPUTE
#undef BODY

  float* dst = part + (size_t)zz * (NN*256);
  #pragma unroll
  for (int mf=0; mf<4; mf++)
    #pragma unroll
    for (int nf=0; nf<4; nf++)
      #pragma unroll
      for (int q=0;q<4;q++){
        int row = m0 + wm*64 + mf*16 + g*4 + q;
        int col = n0 + wn*64 + nf*16 + r;
        dst[row*256 + col] = acc[mf][nf][q];
      }
}

// ---- K5: out = bias + sum_z partial[z] ----
__global__ __launch_bounds__(256) void k_reduce(const float* __restrict__ part, const float* __restrict__ bias,
                                                float* __restrict__ out){
  int i = blockIdx.x*256 + threadIdx.x;
  float4 s0 = reinterpret_cast<const float4*>(part          )[i];
  float4 s1 = reinterpret_cast<const float4*>(part + 2097152)[i];
  float4 s2 = reinterpret_cast<const float4*>(part + 4194304)[i];
  float4 s3 = reinterpret_cast<const float4*>(part + 6291456)[i];
  float4 bb = reinterpret_cast<const float4*>(bias)[i & 63];
  float4 o;
  o.x = s0.x+s1.x+s2.x+s3.x+bb.x;
  o.y = s0.y+s1.y+s2.y+s3.y+bb.y;
  o.z = s0.z+s1.z+s2.z+s3.z+bb.z;
  o.w = s0.w+s1.w+s2.w+s3.w+bb.w;
  reinterpret_cast<float4*>(out)[i] = o;
}

extern "C" void kernel_launch(void* const* d_in, const int* in_sizes, int n_in,
                              void* d_out, int out_size, void* d_ws, size_t ws_size,
                              hipStream_t stream) {
  const float* X    = (const float*)d_in[0];
  const float* S    = (const float*)d_in[1];
  const float* W    = (const float*)d_in[2];
  const float* bias = (const float*)d_in[3];
  float* out = (float*)d_out;
  char* ws = (char*)d_ws;
  u32*   maskT = (u32*)  (ws + 0);         //  8 MiB  [256 jwords][8192 i]
  u16*   Yt    = (u16*)  (ws + 8388608);   //  4 MiB  bf16 [256 f][8192 j]
  float* snorm = (float*)(ws + 12582912);  // 512 KiB
  float* dinvF = (float*)(ws + 13107200);  //  32 KiB
  float* part  = (float*)(ws + 13139968);  //  32 MiB fp32 [4][8192][256]

  k_norm  <<<dim3(32),     dim3(256), 0, stream>>>(S, snorm);
  k_maskT3<<<dim3(528),    dim3(256), 0, stream>>>(snorm, maskT);
  k_deg   <<<dim3(256),    dim3(256), 0, stream>>>(maskT, dinvF);
  k_ygemm <<<dim3(8,64),   dim3(128), 0, stream>>>(X, W, dinvF, Yt);
  k_agg   <<<dim3(64,2,4), dim3(256), 0, stream>>>(Yt, maskT, part);
  k_reduce<<<dim3(2048),   dim3(256), 0, stream>>>(part, bias, out);
}

// Round 7
// 101.767 us; speedup vs baseline: 2.2907x; 1.0341x over previous
//
#include <hip/hip_runtime.h>
#include <hip/hip_bf16.h>

typedef __attribute__((ext_vector_type(8))) short short8;
typedef __attribute__((ext_vector_type(4))) float f32x4;
typedef __attribute__((ext_vector_type(4))) unsigned int u32x4;
typedef unsigned short u16;
typedef unsigned int   u32;
typedef unsigned long long u64;
typedef unsigned char  u8;

#define NN 8192
#define THRESH 0.1f

__device__ __forceinline__ u16 f2bf(float f){
  __hip_bfloat16 h = __float2bfloat16(f);
  u16 u; __builtin_memcpy(&u, &h, 2); return u;
}

// ---- K1: normalize state rows ----
__global__ __launch_bounds__(256) void k_norm(const float* __restrict__ st, float* __restrict__ sn){
  int i = blockIdx.x*256 + threadIdx.x;
  const float4* s4 = reinterpret_cast<const float4*>(st + i*16);
  float4 v[4]; float ss = 0.f;
  #pragma unroll
  for (int q=0;q<4;q++){ v[q]=s4[q]; ss += v[q].x*v[q].x+v[q].y*v[q].y+v[q].z*v[q].z+v[q].w*v[q].w; }
  float inv = 1.0f/(sqrtf(ss) + 1e-12f);
  float4* d4 = reinterpret_cast<float4*>(sn + i*16);
  #pragma unroll
  for (int q=0;q<4;q++){ float4 o; o.x=v[q].x*inv; o.y=v[q].y*inv; o.z=v[q].z*inv; o.w=v[q].w*inv; d4[q]=o; }
}

// ---- K2: symmetric tile mask (proven maskT2 math). Wave = 128 i (2 rows/lane) x 64 j,
// upper-tri tiles (J0>=I0). j-rows staged per-wave in LDS, broadcast ds_read_b128
// (no reliance on compiler scalar-load selection). 1040 blocks -> ~4 blocks/CU. ----
__global__ __launch_bounds__(256) void k_maskT4(const float* __restrict__ sn, u32* __restrict__ maskT){
  __shared__ float sjtA[4*64*20];                // 4 waves x 64 rows x stride 20 floats
  int tid  = threadIdx.x;
  int lane = tid & 63;
  int wid  = tid >> 6;
  int t = __builtin_amdgcn_readfirstlane((int)blockIdx.x*4 + wid);  // tile id 0..4159
  // decode t -> k (I-block of 128), J-block of 64; C(k) = k*(129-k)
  int k = (int)((129.0f - sqrtf((float)(16641 - 4*t))) * 0.5f);
  k = k < 0 ? 0 : (k > 63 ? 63 : k);
  while (k*(129-k) > t) --k;
  while ((k+1)*(128-k) <= t) ++k;
  int I0 = k << 7;
  int J0 = ((k<<1) + (t - k*(129-k))) << 6;

  // stage this wave's 64 j-rows into LDS (wave-private; no cross-wave sync needed)
  float* sjt = sjtA + wid*1280;
  #pragma unroll
  for (int s=0;s<4;s++){
    int row = s*16 + (lane>>2);
    float4 v = *reinterpret_cast<const float4*>(sn + (J0+row)*16 + (lane&3)*4);
    *reinterpret_cast<float4*>(sjt + row*20 + (lane&3)*4) = v;
  }

  float siA[16], siB[16];
  #pragma unroll
  for (int q=0;q<4;q++){
    float4 a = reinterpret_cast<const float4*>(sn + (I0+lane)*16)[q];
    float4 b = reinterpret_cast<const float4*>(sn + (I0+64+lane)*16)[q];
    siA[4*q]=a.x; siA[4*q+1]=a.y; siA[4*q+2]=a.z; siA[4*q+3]=a.w;
    siB[4*q]=b.x; siB[4*q+1]=b.y; siB[4*q+2]=b.z; siB[4*q+3]=b.w;
  }

  u32 wA0=0, wA1=0, wB0=0, wB1=0;        // row-words: rows iA,iB over 64 j-bits
  u32 cAlo=0, cAhi=0, cBlo=0, cBhi=0;    // col-words: row j=J0+lane over 128 i-bits
  #pragma unroll
  for (int jh=0; jh<2; ++jh){
    u32 wa = 0, wb = 0;
    #pragma unroll 4
    for (int j2=0; j2<32; ++j2){
      int jl = jh*32 + j2;
      const float* sp = sjt + jl*20;               // uniform addr -> LDS broadcast
      float4 p0 = *reinterpret_cast<const float4*>(sp);
      float4 p1 = *reinterpret_cast<const float4*>(sp+4);
      float4 p2 = *reinterpret_cast<const float4*>(sp+8);
      float4 p3 = *reinterpret_cast<const float4*>(sp+12);
      float dA0 = p0.x*siA[0]  + p0.y*siA[1]  + p0.z*siA[2]  + p0.w*siA[3];
      float dA1 = p1.x*siA[4]  + p1.y*siA[5]  + p1.z*siA[6]  + p1.w*siA[7];
      float dA2 = p2.x*siA[8]  + p2.y*siA[9]  + p2.z*siA[10] + p2.w*siA[11];
      float dA3 = p3.x*siA[12] + p3.y*siA[13] + p3.z*siA[14] + p3.w*siA[15];
      float dB0 = p0.x*siB[0]  + p0.y*siB[1]  + p0.z*siB[2]  + p0.w*siB[3];
      float dB1 = p1.x*siB[4]  + p1.y*siB[5]  + p1.z*siB[6]  + p1.w*siB[7];
      float dB2 = p2.x*siB[8]  + p2.y*siB[9]  + p2.z*siB[10] + p2.w*siB[11];
      float dB3 = p3.x*siB[12] + p3.y*siB[13] + p3.z*siB[14] + p3.w*siB[15];
      float dA = (dA0+dA1)+(dA2+dA3);
      float dB = (dB0+dB1)+(dB2+dB3);
      bool pA = (dA*dA >= THRESH);
      bool pB = (dB*dB >= THRESH);
      u64 balA = __ballot(pA);
      u64 balB = __ballot(pB);
      wa |= pA ? (1u<<j2) : 0u;
      wb |= pB ? (1u<<j2) : 0u;
      bool me = (lane == jl);
      cAlo = me ? (u32)balA        : cAlo;
      cAhi = me ? (u32)(balA>>32)  : cAhi;
      cBlo = me ? (u32)balB        : cBlo;
      cBhi = me ? (u32)(balB>>32)  : cBhi;
    }
    if (jh==0){ wA0=wa; wB0=wb; } else { wA1=wa; wB1=wb; }
  }

  // self-loop clearing (J0>=I0 always)
  {
    u32 relA = (u32)(I0 + lane - J0);
    if (relA < 64u){ if (relA < 32u) wA0 &= ~(1u<<relA); else wA1 &= ~(1u<<(relA-32)); }
    u32 relB = (u32)(I0 + 64 + lane - J0);
    if (relB < 64u){ if (relB < 32u) wB0 &= ~(1u<<relB); else wB1 &= ~(1u<<(relB-32)); }
    int jg0 = J0 + lane;
    u32 off = (u32)(jg0 - I0);
    if (off < 128u){
      u32 bit = 1u<<(off&31);
      if (off < 32u) cAlo &= ~bit; else if (off < 64u) cAhi &= ~bit;
      else if (off < 96u) cBlo &= ~bit; else cBhi &= ~bit;
    }
  }

  int iA = I0 + lane, iB = iA + 64, jg = J0 + lane;
  size_t jw = (size_t)(J0>>5)*NN;
  size_t iw = (size_t)(I0>>5)*NN;
  maskT[jw      + iA] = wA0;  maskT[jw + NN + iA] = wA1;
  maskT[jw      + iB] = wB0;  maskT[jw + NN + iB] = wB1;
  maskT[iw        + jg] = cAlo; maskT[iw +   NN + jg] = cAhi;
  maskT[iw + 2*NN + jg] = cBlo; maskT[iw + 3*NN + jg] = cBhi;
}

// ---- K2b: deg[i] via popcount; dinv = 1/(deg+eps) ----
__global__ __launch_bounds__(256) void k_deg(const u32* __restrict__ maskT, float* __restrict__ dinvF){
  __shared__ u32 red[256];
  int tid = threadIdx.x;
  int il = tid & 31, ws = tid >> 5;
  int i = blockIdx.x*32 + il;
  u32 s = 0;
  #pragma unroll 8
  for (int w = ws*32; w < ws*32 + 32; ++w) s += __popc(maskT[(size_t)w*NN + i]);
  red[tid] = s;
  __syncthreads();
  if (tid < 32){
    u32 tot = 0;
    #pragma unroll
    for (int g=0; g<8; ++g) tot += red[g*32 + tid];
    dinvF[i] = 1.0f/((float)tot + 1e-6f);
  }
}

// ---- K3: Yt[f][j] = dinv[j] * sum_k X[j,k]*W[f,k]  (bf16, j-contiguous) ----
__global__ __launch_bounds__(128) void k_ygemm(const float* __restrict__ X, const float* __restrict__ W,
                                               const float* __restrict__ dinvF, u16* __restrict__ Yt){
  int tid = threadIdx.x;
  int lane = tid & 63;
  int r = lane & 15, g = lane >> 4;
  int wj = tid >> 6;
  int f0 = blockIdx.x * 32;
  int j0 = blockIdx.y * 128 + wj * 64;
  f32x4 acc[2][4] = {};
  #pragma unroll
  for (int k0 = 0; k0 < 256; k0 += 32){
    short8 a[2], b[4];
    #pragma unroll
    for (int af=0; af<2; af++){
      const float* p = W + (f0 + af*16 + r)*256 + k0 + g*8;
      float4 u = reinterpret_cast<const float4*>(p)[0];
      float4 v = reinterpret_cast<const float4*>(p)[1];
      short8 tt;
      tt[0]=(short)f2bf(u.x); tt[1]=(short)f2bf(u.y); tt[2]=(short)f2bf(u.z); tt[3]=(short)f2bf(u.w);
      tt[4]=(short)f2bf(v.x); tt[5]=(short)f2bf(v.y); tt[6]=(short)f2bf(v.z); tt[7]=(short)f2bf(v.w);
      a[af] = tt;
    }
    #pragma unroll
    for (int bf=0; bf<4; bf++){
      const float* p = X + (j0 + bf*16 + r)*256 + k0 + g*8;
      float4 u = reinterpret_cast<const float4*>(p)[0];
      float4 v = reinterpret_cast<const float4*>(p)[1];
      short8 tt;
      tt[0]=(short)f2bf(u.x); tt[1]=(short)f2bf(u.y); tt[2]=(short)f2bf(u.z); tt[3]=(short)f2bf(u.w);
      tt[4]=(short)f2bf(v.x); tt[5]=(short)f2bf(v.y); tt[6]=(short)f2bf(v.z); tt[7]=(short)f2bf(v.w);
      b[bf] = tt;
    }
    #pragma unroll
    for (int af=0; af<2; af++)
      #pragma unroll
      for (int bf=0; bf<4; bf++)
        acc[af][bf] = __builtin_amdgcn_mfma_f32_16x16x32_bf16(a[af], b[bf], acc[af][bf], 0, 0, 0);
  }
  float ds[4];
  #pragma unroll
  for (int bf=0;bf<4;bf++) ds[bf] = dinvF[j0 + bf*16 + r];
  #pragma unroll
  for (int af=0; af<2; af++)
    #pragma unroll
    for (int bf=0; bf<4; bf++)
      #pragma unroll
      for (int q=0;q<4;q++)
        Yt[(f0 + af*16 + g*4 + q)*NN + j0 + bf*16 + r] = f2bf(acc[af][bf][q] * ds[bf]);
}

// ---- K4: partial[z] = M @ Y. 3-buffer depth-2 global_load_lds pipeline, counted vmcnt.
// 3 buffers (51 KB LDS) -> 3 blocks/CU -> 3 waves/SIMD from DIFFERENT blocks
// (barrier-decoupled overlap). Buffer (t+2)%3 is free at stage time: its tile t-1
// was consumed before the barrier that ended step t-1. ----
#define VMCNT(N) asm volatile("s_waitcnt vmcnt(" #N ")" ::: "memory")
__global__ __launch_bounds__(256) void k_agg(const u16* __restrict__ Yt, const u32* __restrict__ maskT,
                                             float* __restrict__ part){
  __shared__ u8  ldsB[3][16384];  // [buf][128 n-rows][64 k] bf16, chunk-XOR swizzle via source
  __shared__ u32 ldsM[3][256];    // [buf][row*2 + kword]  (DMA lands interleaved)
  int tid = threadIdx.x;
  int lane = tid & 63, wid = tid >> 6;
  int r = lane & 15, g = lane >> 4;
  int wm = wid >> 1, wn = wid & 1;
  // XCD swizzle: 8 groups (n0,zz) x 64 m-blocks; p%8 pins each (n0,zz) group to one XCD.
  int p = (int)blockIdx.x + 64*((int)blockIdx.y + 2*(int)blockIdx.z);
  int gq = p & 7, idx = p >> 3;
  int m0 = idx*128;
  int n0 = (gq & 1)*128;
  int zz = gq >> 1;
  int kbase = zz*2048;
  f32x4 acc[4][4] = {};

  // per-lane global base addresses at step t=0
  const char* ytb[4];
  #pragma unroll
  for (int is=0; is<4; ++is){
    int rw = wid*32 + is*8 + (lane>>3);
    ytb[is] = (const char*)(Yt + ((size_t)(n0+rw) << 13) + (size_t)kbase + (size_t)(((lane&7) ^ (rw&7))<<3));
  }
  const char* mkb = (const char*)(maskT + (size_t)((kbase>>5) + (lane&1))*NN + m0 + wid*32 + (lane>>1));

#define GSTAGE(BUF, T) do { \
    _Pragma("unroll") \
    for (int is=0; is<4; ++is) \
      __builtin_amdgcn_global_load_lds((const __attribute__((address_space(1))) void*)(ytb[is] + (T)*128), \
          (__attribute__((address_space(3))) void*)&ldsB[BUF][wid*4096 + is*1024], 16, 0, 0); \
    __builtin_amdgcn_global_load_lds((const __attribute__((address_space(1))) void*)(mkb + (T)*65536), \
        (__attribute__((address_space(3))) void*)&ldsM[BUF][wid*64], 4, 0, 0); \
  } while(0)

#define COMPUTE(BUF) do { \
    short8 bfrag[2][4]; \
    _Pragma("unroll") \
    for (int kk=0; kk<2; ++kk) \
      _Pragma("unroll") \
      for (int nf=0; nf<4; ++nf) \
        bfrag[kk][nf] = *reinterpret_cast<const short8*>(&ldsB[BUF][(wn*64+nf*16+r)*128 + (((kk*4+g)^(r&7))<<4)]); \
    __builtin_amdgcn_s_setprio(1); \
    _Pragma("unroll") \
    for (int mf=0; mf<4; ++mf){ \
      u64 mw = *reinterpret_cast<const u64*>(&ldsM[BUF][(wm*64+mf*16+r)*2]); \
      _Pragma("unroll") \
      for (int kk=0; kk<2; ++kk){ \
        u32 byte = ((u32)(mw >> (kk*32)) >> (g*8)) & 0xffu; \
        u32 x = byte * 0x8001u; \
        u32x4 wv; \
        _Pragma("unroll") \
        for (int pp=0; pp<4; ++pp) wv[pp] = ((x >> (2*pp)) & 0x00010001u) * 0x3F80u; \
        short8 a = __builtin_bit_cast(short8, wv); \
        _Pragma("unroll") \
        for (int nf=0; nf<4; ++nf) \
          acc[mf][nf] = __builtin_amdgcn_mfma_f32_16x16x32_bf16(a, bfrag[kk][nf], acc[mf][nf], 0, 0, 0); \
      } \
    } \
    __builtin_amdgcn_s_setprio(0); \
  } while(0)

#define BODY(CB, SB, T) do { \
    GSTAGE(SB, (T)+2); \
    COMPUTE(CB); \
    VMCNT(5); \
    __builtin_amdgcn_s_barrier(); \
  } while(0)

  // prologue: stage t=0,1
  GSTAGE(0, 0);
  GSTAGE(1, 1);
  VMCNT(5);                       // stage(0) landed; stage(1) in flight
  __builtin_amdgcn_s_barrier();

  #pragma unroll 1
  for (int t = 0; t < 30; t += 3){
    BODY(0, 2, t);
    BODY(1, 0, t+1);
    BODY(2, 1, t+2);
  }
  // loop staged T = 2..31; tiles 0..29 computed
  COMPUTE(0);                     // tile 30
  VMCNT(0);                       // stage(31) fully landed (per-wave)
  __builtin_amdgcn_s_barrier();   // ...and cross-wave
  COMPUTE(1);                     // tile 31

#undef GSTAGE
#undef COMPUTE
#undef BODY

  float* dst = part + (size_t)zz * (NN*256);
  #pragma unroll
  for (int mf=0; mf<4; mf++)
    #pragma unroll
    for (int nf=0; nf<4; nf++)
      #pragma unroll
      for (int q=0;q<4;q++){
        int row = m0 + wm*64 + mf*16 + g*4 + q;
        int col = n0 + wn*64 + nf*16 + r;
        dst[row*256 + col] = acc[mf][nf][q];
      }
}

// ---- K5: out = bias + sum_z partial[z] ----
__global__ __launch_bounds__(256) void k_reduce(const float* __restrict__ part, const float* __restrict__ bias,
                                                float* __restrict__ out){
  int i = blockIdx.x*256 + threadIdx.x;
  float4 s0 = reinterpret_cast<const float4*>(part          )[i];
  float4 s1 = reinterpret_cast<const float4*>(part + 2097152)[i];
  float4 s2 = reinterpret_cast<const float4*>(part + 4194304)[i];
  float4 s3 = reinterpret_cast<const float4*>(part + 6291456)[i];
  float4 bb = reinterpret_cast<const float4*>(bias)[i & 63];
  float4 o;
  o.x = s0.x+s1.x+s2.x+s3.x+bb.x;
  o.y = s0.y+s1.y+s2.y+s3.y+bb.y;
  o.z = s0.z+s1.z+s2.z+s3.z+bb.z;
  o.w = s0.w+s1.w+s2.w+s3.w+bb.w;
  reinterpret_cast<float4*>(out)[i] = o;
}

extern "C" void kernel_launch(void* const* d_in, const int* in_sizes, int n_in,
                              void* d_out, int out_size, void* d_ws, size_t ws_size,
                              hipStream_t stream) {
  const float* X    = (const float*)d_in[0];
  const float* S    = (const float*)d_in[1];
  const float* W    = (const float*)d_in[2];
  const float* bias = (const float*)d_in[3];
  float* out = (float*)d_out;
  char* ws = (char*)d_ws;
  u32*   maskT = (u32*)  (ws + 0);         //  8 MiB  [256 jwords][8192 i]
  u16*   Yt    = (u16*)  (ws + 8388608);   //  4 MiB  bf16 [256 f][8192 j]
  float* snorm = (float*)(ws + 12582912);  // 512 KiB
  float* dinvF = (float*)(ws + 13107200);  //  32 KiB
  float* part  = (float*)(ws + 13139968);  //  32 MiB fp32 [4][8192][256]

  k_norm  <<<dim3(32),     dim3(256), 0, stream>>>(S, snorm);
  k_maskT4<<<dim3(1040),   dim3(256), 0, stream>>>(snorm, maskT);
  k_deg   <<<dim3(256),    dim3(256), 0, stream>>>(maskT, dinvF);
  k_ygemm <<<dim3(8,64),   dim3(128), 0, stream>>>(X, W, dinvF, Yt);
  k_agg   <<<dim3(64,2,4), dim3(256), 0, stream>>>(Yt, maskT, part);
  k_reduce<<<dim3(2048),   dim3(256), 0, stream>>>(part, bias, out);
}